// Round 1
// baseline (30699.542 us; speedup 1.0000x reference)
//
#include <hip/hip_runtime.h>

// ---------------------------------------------------------------------------
// LSTM B=32, S=2048, E=512, H=512  (gates 4H=2048), fp32 in/out.
// Plan:
//   prep_kernel : permute+sum biases, zero h hi/lo planes, zero barrier
//                 counter, emit lengths as floats into d_out.
//   xproj_gemm  : xp[t][b][n'] (bf16) = x @ W_ih^T + bias, split-bf16 MFMA
//                 (hi+lo, 3 mfma terms) so only the final bf16 store rounds.
//                 n' is a permuted gate index: n' = ug*16 + gate*4 + ul,
//                 unit = ug*4+ul  -> recurrent reads are contiguous 32B runs.
//   lstm_rec    : persistent kernel, 256 WGs x 256 thr (all co-resident on
//                 256 CUs). WG = (batch-half bh, unit-group ug of 4 units).
//                 W_hh rows (16) held in VGPRs as bf16 hi/lo frags. Per step:
//                 stage h (bf16 hi/lo planes) -> LDS (xor-swizzled),
//                 16x16 tile via mfma_f32_16x16x32_bf16 (K split on 4 waves,
//                 3-term split product), LDS reduce, wave0 does gates/c/h,
//                 publishes h hi/lo, then device-wide sense-free monotonic
//                 atomic barrier (agent scope, release/acquire fences).
// ---------------------------------------------------------------------------

typedef __attribute__((ext_vector_type(8))) __bf16 bf16x8;
typedef __attribute__((ext_vector_type(8))) short short8;
typedef __attribute__((ext_vector_type(4))) float floatx4;

#define NWG 256u

// ws layout (bytes)
#define XP_OFF   0ull
#define XP_BYTES (2048ull * 32ull * 2048ull * 2ull)   // 268,435,456
#define HHI_OFF  (XP_OFF + XP_BYTES)                  // 32*512 bf16
#define HLO_OFF  (HHI_OFF + 32768ull)
#define BIAS_OFF (HLO_OFF + 32768ull)                 // 2048 fp32
#define CNT_OFF  (BIAS_OFF + 8192ull)
#define WS_NEED  (CNT_OFF + 64ull)

// d_out layout (fp32 elements): out[32][2048][1][512], lengths[32], hidden[1][32][512]
#define OUT_ELEMS    33554432
#define LEN_OFF_F    33554432
#define HIDDEN_OFF_F 33554464

__device__ inline float sigm(float x) { return 1.f / (1.f + __expf(-x)); }
__device__ inline float tanh_(float x) {
  float e = __expf(-2.f * fabsf(x));
  float r = (1.f - e) / (1.f + e);
  return x >= 0.f ? r : -r;
}

__device__ inline void cvt_hilo8(const float* v, bf16x8& hi, bf16x8& lo) {
#pragma unroll
  for (int i = 0; i < 8; ++i) {
    __bf16 h = (__bf16)v[i];
    hi[i] = h;
    lo[i] = (__bf16)(v[i] - (float)h);
  }
}

// ---------------------------------------------------------------------------
__global__ __launch_bounds__(256) void prep_kernel(
    const float* __restrict__ bih, const float* __restrict__ bhh,
    const int* __restrict__ len, float* __restrict__ biasp,
    short* __restrict__ hhi, short* __restrict__ hlo,
    unsigned* __restrict__ cnt, float* __restrict__ outf) {
  const int tid = threadIdx.x;
  for (int i = tid; i < 2048; i += 256) {
    // n' = ug*16 + g*4 + ul  ->  row = g*512 + ug*4 + ul
    int rowg = ((i >> 2) & 3) * 512 + (i >> 4) * 4 + (i & 3);
    biasp[i] = bih[rowg] + bhh[rowg];
  }
  for (int i = tid; i < 16384; i += 256) { hhi[i] = 0; hlo[i] = 0; }
  if (tid < 32) outf[LEN_OFF_F + tid] = (float)len[tid];
  if (tid == 0) *cnt = 0u;
}

// ---------------------------------------------------------------------------
// xp GEMM: M=65536 (b*2048+s), N=2048 (n'), K=512. Tile 64x64, BK=32,
// 256 threads = 4 waves, each wave one 16-row band, 4 column tiles.
__global__ __launch_bounds__(256) void xproj_gemm(
    const float* __restrict__ x, const float* __restrict__ Wih,
    const float* __restrict__ biasp, __bf16* __restrict__ xp) {
  __shared__ short Ash[64 * 40], Asl[64 * 40], Bsh[64 * 40], Bsl[64 * 40];
  const int tid = threadIdx.x;
  const int w = tid >> 6, lane = tid & 63, ln = lane & 15, kq = lane >> 4;
  const int ntile = blockIdx.x & 31, mtile = blockIdx.x >> 5;
  const int srow = tid >> 2, sseg = tid & 3;

  const size_t a_base = (size_t)(mtile * 64 + srow) * 512 + sseg * 8;
  const int np_s = ntile * 64 + srow;
  const int rowg = ((np_s >> 2) & 3) * 512 + (np_s >> 4) * 4 + (np_s & 3);
  const size_t b_base = (size_t)rowg * 512 + sseg * 8;

  floatx4 acc[4] = {{0,0,0,0},{0,0,0,0},{0,0,0,0},{0,0,0,0}};

  for (int k0 = 0; k0 < 512; k0 += 32) {
    floatx4 a0 = *(const floatx4*)(x + a_base + k0);
    floatx4 a1 = *(const floatx4*)(x + a_base + k0 + 4);
    floatx4 b0 = *(const floatx4*)(Wih + b_base + k0);
    floatx4 b1 = *(const floatx4*)(Wih + b_base + k0 + 4);
    __syncthreads();  // previous iter's frag reads done before overwrite
    {
      float va[8] = {a0[0],a0[1],a0[2],a0[3],a1[0],a1[1],a1[2],a1[3]};
      bf16x8 hi, lo; cvt_hilo8(va, hi, lo);
      *(short8*)&Ash[srow * 40 + sseg * 8] = __builtin_bit_cast(short8, hi);
      *(short8*)&Asl[srow * 40 + sseg * 8] = __builtin_bit_cast(short8, lo);
      float vb[8] = {b0[0],b0[1],b0[2],b0[3],b1[0],b1[1],b1[2],b1[3]};
      cvt_hilo8(vb, hi, lo);
      *(short8*)&Bsh[srow * 40 + sseg * 8] = __builtin_bit_cast(short8, hi);
      *(short8*)&Bsl[srow * 40 + sseg * 8] = __builtin_bit_cast(short8, lo);
    }
    __syncthreads();
    bf16x8 ah = __builtin_bit_cast(bf16x8, *(const short8*)&Ash[(16 * w + ln) * 40 + kq * 8]);
    bf16x8 al = __builtin_bit_cast(bf16x8, *(const short8*)&Asl[(16 * w + ln) * 40 + kq * 8]);
#pragma unroll
    for (int nt = 0; nt < 4; ++nt) {
      bf16x8 bh = __builtin_bit_cast(bf16x8, *(const short8*)&Bsh[(nt * 16 + ln) * 40 + kq * 8]);
      bf16x8 bl = __builtin_bit_cast(bf16x8, *(const short8*)&Bsl[(nt * 16 + ln) * 40 + kq * 8]);
      acc[nt] = __builtin_amdgcn_mfma_f32_16x16x32_bf16(ah, bh, acc[nt], 0, 0, 0);
      acc[nt] = __builtin_amdgcn_mfma_f32_16x16x32_bf16(al, bh, acc[nt], 0, 0, 0);
      acc[nt] = __builtin_amdgcn_mfma_f32_16x16x32_bf16(ah, bl, acc[nt], 0, 0, 0);
    }
  }
#pragma unroll
  for (int nt = 0; nt < 4; ++nt) {
    const int npg = ntile * 64 + nt * 16 + ln;
    const float bs = biasp[npg];
#pragma unroll
    for (int r = 0; r < 4; ++r) {
      const int m = mtile * 64 + w * 16 + kq * 4 + r;  // D row = (lane>>4)*4+reg
      const int s = m & 2047, b = m >> 11;
      xp[(size_t)(s * 32 + b) * 2048 + npg] = (__bf16)(acc[nt][r] + bs);
    }
  }
}

// ---------------------------------------------------------------------------
__global__ __launch_bounds__(256) void lstm_rec(
    const float* __restrict__ Whh, const int* __restrict__ lengths,
    const __bf16* __restrict__ xp, float* __restrict__ out,
    float* __restrict__ hid, __bf16* __restrict__ hhi,
    __bf16* __restrict__ hlo, unsigned* __restrict__ cnt) {
  __shared__ short Hh[16 * 512];   // [m][k] bf16 hi, xor-swizzled 16B granules
  __shared__ short Hl[16 * 512];
  __shared__ float Part[4 * 16 * 16];  // [wave][m][n]
  __shared__ short Xps[256];           // [m][n] bf16

  const int tid = threadIdx.x;
  const int w = tid >> 6, lane = tid & 63, ln = lane & 15, kq = lane >> 4;
  const int bh = blockIdx.x & 1, ug = blockIdx.x >> 1;
  const int b0 = bh * 16;

  // Persistent W_hh fragments (B operand): n = ln, row = gate*512 + ug*4 + ul
  const int rowg = (ln >> 2) * 512 + ug * 4 + (ln & 3);
  bf16x8 whi[4], wlo[4];
#pragma unroll
  for (int kc = 0; kc < 4; ++kc) {
    const int k = w * 128 + kc * 32 + kq * 8;
    floatx4 f0 = *(const floatx4*)(Whh + (size_t)rowg * 512 + k);
    floatx4 f1 = *(const floatx4*)(Whh + (size_t)rowg * 512 + k + 4);
    float v[8] = {f0[0],f0[1],f0[2],f0[3],f1[0],f1[1],f1[2],f1[3]};
    cvt_hilo8(v, whi[kc], wlo[kc]);
  }

  const int m_d = tid >> 2, ul = tid & 3;  // wave0 elementwise ownership
  int lenb = 0;
  if (tid < 64) lenb = lengths[b0 + m_d];
  float cst = 0.f;

  const int sm = tid >> 4, sq = tid & 15;  // staging: 16 thr/row, 4 granules each
  const short* ghi = (const short*)hhi + (size_t)(b0 + sm) * 512;
  const short* glo = (const short*)hlo + (size_t)(b0 + sm) * 512;

  for (int t = 0; t < 2048; ++t) {
    // ---- stage xp row-slice (512B) and h half (16KB hi + 16KB lo) ----
    if (tid < 64) {
      const unsigned long long v = *(const unsigned long long*)(
          (const short*)xp + (size_t)(t * 32 + b0 + m_d) * 2048 + ug * 16 + ul * 4);
      *(unsigned long long*)&Xps[m_d * 16 + ul * 4] = v;
    }
#pragma unroll
    for (int i = 0; i < 4; ++i) {
      const int g = sq + 16 * i;
      short8 vh = *(const short8*)(ghi + g * 8);
      short8 vl = *(const short8*)(glo + g * 8);
      const int d = sm * 512 + ((g ^ (sm & 7)) * 8);
      *(short8*)&Hh[d] = vh;
      *(short8*)&Hl[d] = vl;
    }
    __syncthreads();
    // ---- MFMA: tile M=16 (batches), N=16 (gate rows), wave w has K-slice ----
    floatx4 acc = {0, 0, 0, 0};
#pragma unroll
    for (int kc = 0; kc < 4; ++kc) {
      const int g = w * 16 + kc * 4 + kq;
      const int d = ln * 512 + ((g ^ (ln & 7)) * 8);
      bf16x8 ah = __builtin_bit_cast(bf16x8, *(const short8*)&Hh[d]);
      bf16x8 al = __builtin_bit_cast(bf16x8, *(const short8*)&Hl[d]);
      acc = __builtin_amdgcn_mfma_f32_16x16x32_bf16(ah, whi[kc], acc, 0, 0, 0);
      acc = __builtin_amdgcn_mfma_f32_16x16x32_bf16(al, whi[kc], acc, 0, 0, 0);
      acc = __builtin_amdgcn_mfma_f32_16x16x32_bf16(ah, wlo[kc], acc, 0, 0, 0);
    }
#pragma unroll
    for (int r = 0; r < 4; ++r)
      Part[w * 256 + (kq * 4 + r) * 16 + ln] = acc[r];
    __syncthreads();
    // ---- elementwise on wave0: one (batch,unit) per thread ----
    if (tid < 64) {
      float pre[4];
#pragma unroll
      for (int g = 0; g < 4; ++g) {
        const int idx = m_d * 16 + g * 4 + ul;
        float xv = (float)__builtin_bit_cast(__bf16, Xps[idx]);
        pre[g] = xv + Part[idx] + Part[256 + idx] + Part[512 + idx] + Part[768 + idx];
      }
      const float gi = sigm(pre[0]);
      const float gf = sigm(pre[1]);
      const float gg = tanh_(pre[2]);
      const float go = sigm(pre[3]);
      cst = gf * cst + gi * gg;
      const float hv = go * tanh_(cst);
      const int b = b0 + m_d, u = ug * 4 + ul;
      out[((size_t)b * 2048 + t) * 512 + u] = (t < lenb) ? hv : 0.f;
      if (t == lenb - 1) hid[b * 512 + u] = hv;
      const __bf16 hb = (__bf16)hv;
      hhi[b * 512 + u] = hb;
      hlo[b * 512 + u] = (__bf16)(hv - (float)hb);
    }
    // ---- device-wide barrier (monotonic counter, agent scope) ----
    if (tid == 0) {
      __builtin_amdgcn_fence(__ATOMIC_RELEASE, "agent");
      __hip_atomic_fetch_add(cnt, 1u, __ATOMIC_RELAXED, __HIP_MEMORY_SCOPE_AGENT);
      const unsigned tgt = NWG * (unsigned)(t + 1);
      while (__hip_atomic_load(cnt, __ATOMIC_RELAXED, __HIP_MEMORY_SCOPE_AGENT) < tgt)
        __builtin_amdgcn_s_sleep(2);
      __builtin_amdgcn_fence(__ATOMIC_ACQUIRE, "agent");
    }
    __syncthreads();
  }
}

// ---------------------------------------------------------------------------
extern "C" void kernel_launch(void* const* d_in, const int* in_sizes, int n_in,
                              void* d_out, int out_size, void* d_ws, size_t ws_size,
                              hipStream_t stream) {
  const float* x = (const float*)d_in[0];
  const int* lengths = (const int*)d_in[1];
  const float* Wih = (const float*)d_in[2];
  const float* Whh = (const float*)d_in[3];
  const float* bih = (const float*)d_in[4];
  const float* bhh = (const float*)d_in[5];
  float* outf = (float*)d_out;
  char* ws = (char*)d_ws;
  if (ws_size < WS_NEED) return;  // ws too small: fail visibly

  float* biasp = (float*)(ws + BIAS_OFF);
  __bf16* xp = (__bf16*)(ws + XP_OFF);
  __bf16* hhi = (__bf16*)(ws + HHI_OFF);
  __bf16* hlo = (__bf16*)(ws + HLO_OFF);
  unsigned* cnt = (unsigned*)(ws + CNT_OFF);

  prep_kernel<<<1, 256, 0, stream>>>(bih, bhh, lengths, biasp,
                                     (short*)hhi, (short*)hlo, cnt, outf);
  xproj_gemm<<<32768, 256, 0, stream>>>(x, Wih, biasp, xp);
  lstm_rec<<<NWG, 256, 0, stream>>>(Whh, lengths, xp, outf,
                                    outf + HIDDEN_OFF_F, hhi, hlo, cnt);
}

// Round 2
// 11098.339 us; speedup vs baseline: 2.7661x; 2.7661x over previous
//
#include <hip/hip_runtime.h>

// ---------------------------------------------------------------------------
// LSTM B=32, S=2048, E=512, H=512 (gates 4H=2048), fp32 in/out.
//   prep_kernel : permuted bias, zero h planes + counters, lengths->floats.
//   xproj_gemm  : xp[t][b][n'] bf16 = x @ W_ih^T + bias (split-bf16 MFMA).
//   lstm_rec    : persistent, 128 WGs x 256 thr. WG = (batch-half bh,
//                 unit-group ug8 of 8 units). W_hh frags in VGPRs (bf16
//                 hi/lo). h exchanged as packed (hi<<16|lo) dwords through
//                 the LLC via relaxed AGENT-scope atomics (sc0 sc1 bypass,
//                 NO fences -> no buffer_wbl2/buffer_inv per step).
//                 Double-buffered h planes; per-half 64-WG barrier;
//                 xp prefetched by wave1 into LDS double buffer.
// ---------------------------------------------------------------------------

typedef __attribute__((ext_vector_type(8))) __bf16 bf16x8;
typedef __attribute__((ext_vector_type(8))) short short8;
typedef __attribute__((ext_vector_type(4))) float floatx4;

// ws layout (bytes)
#define XP_OFF   0ull
#define XP_BYTES (2048ull * 32ull * 2048ull * 2ull)   // 268,435,456
#define HPK_OFF  (XP_OFF + XP_BYTES)                  // 2 planes x 16384 dwords
#define HPK_BYTES (2ull * 16384ull * 4ull)
#define BIAS_OFF (HPK_OFF + HPK_BYTES)
#define CNT_OFF  (BIAS_OFF + 8192ull)                 // cnt[0], cnt[128] (512B apart)
#define WS_NEED  (CNT_OFF + 1024ull)

// d_out layout (fp32): out[32][2048][1][512], lengths[32], hidden[1][32][512]
#define LEN_OFF_F    33554432
#define HIDDEN_OFF_F 33554464

__device__ inline float sigm(float x) { return 1.f / (1.f + __expf(-x)); }
__device__ inline float tanh_(float x) {
  float e = __expf(-2.f * fabsf(x));
  float r = (1.f - e) / (1.f + e);
  return x >= 0.f ? r : -r;
}

__device__ inline void cvt_hilo8(const float* v, bf16x8& hi, bf16x8& lo) {
#pragma unroll
  for (int i = 0; i < 8; ++i) {
    __bf16 h = (__bf16)v[i];
    hi[i] = h;
    lo[i] = (__bf16)(v[i] - (float)h);
  }
}

// ---------------------------------------------------------------------------
__global__ __launch_bounds__(256) void prep_kernel(
    const float* __restrict__ bih, const float* __restrict__ bhh,
    const int* __restrict__ len, float* __restrict__ biasp,
    unsigned* __restrict__ hpk, unsigned* __restrict__ cnt,
    float* __restrict__ outf) {
  const int tid = threadIdx.x;
  for (int i = tid; i < 2048; i += 256) {
    // n' = ug*16 + g*4 + ul (ug = 4-unit group) -> row = g*512 + ug*4 + ul
    int rowg = ((i >> 2) & 3) * 512 + (i >> 4) * 4 + (i & 3);
    biasp[i] = bih[rowg] + bhh[rowg];
  }
  for (int i = tid; i < 32768; i += 256) hpk[i] = 0u;
  if (tid < 32) outf[LEN_OFF_F + tid] = (float)len[tid];
  if (tid == 0) { cnt[0] = 0u; cnt[128] = 0u; }
}

// ---------------------------------------------------------------------------
// xp GEMM: M=65536 (b*2048+s), N=2048 (n'), K=512. Tile 64x64, BK=32.
__global__ __launch_bounds__(256) void xproj_gemm(
    const float* __restrict__ x, const float* __restrict__ Wih,
    const float* __restrict__ biasp, __bf16* __restrict__ xp) {
  __shared__ short Ash[64 * 40], Asl[64 * 40], Bsh[64 * 40], Bsl[64 * 40];
  const int tid = threadIdx.x;
  const int w = tid >> 6, lane = tid & 63, ln = lane & 15, kq = lane >> 4;
  const int ntile = blockIdx.x & 31, mtile = blockIdx.x >> 5;
  const int srow = tid >> 2, sseg = tid & 3;

  const size_t a_base = (size_t)(mtile * 64 + srow) * 512 + sseg * 8;
  const int np_s = ntile * 64 + srow;
  const int rowg = ((np_s >> 2) & 3) * 512 + (np_s >> 4) * 4 + (np_s & 3);
  const size_t b_base = (size_t)rowg * 512 + sseg * 8;

  floatx4 acc[4] = {{0,0,0,0},{0,0,0,0},{0,0,0,0},{0,0,0,0}};

  for (int k0 = 0; k0 < 512; k0 += 32) {
    floatx4 a0 = *(const floatx4*)(x + a_base + k0);
    floatx4 a1 = *(const floatx4*)(x + a_base + k0 + 4);
    floatx4 b0 = *(const floatx4*)(Wih + b_base + k0);
    floatx4 b1 = *(const floatx4*)(Wih + b_base + k0 + 4);
    __syncthreads();
    {
      float va[8] = {a0[0],a0[1],a0[2],a0[3],a1[0],a1[1],a1[2],a1[3]};
      bf16x8 hi, lo; cvt_hilo8(va, hi, lo);
      *(short8*)&Ash[srow * 40 + sseg * 8] = __builtin_bit_cast(short8, hi);
      *(short8*)&Asl[srow * 40 + sseg * 8] = __builtin_bit_cast(short8, lo);
      float vb[8] = {b0[0],b0[1],b0[2],b0[3],b1[0],b1[1],b1[2],b1[3]};
      cvt_hilo8(vb, hi, lo);
      *(short8*)&Bsh[srow * 40 + sseg * 8] = __builtin_bit_cast(short8, hi);
      *(short8*)&Bsl[srow * 40 + sseg * 8] = __builtin_bit_cast(short8, lo);
    }
    __syncthreads();
    bf16x8 ah = __builtin_bit_cast(bf16x8, *(const short8*)&Ash[(16 * w + ln) * 40 + kq * 8]);
    bf16x8 al = __builtin_bit_cast(bf16x8, *(const short8*)&Asl[(16 * w + ln) * 40 + kq * 8]);
#pragma unroll
    for (int nt = 0; nt < 4; ++nt) {
      bf16x8 bh = __builtin_bit_cast(bf16x8, *(const short8*)&Bsh[(nt * 16 + ln) * 40 + kq * 8]);
      bf16x8 bl = __builtin_bit_cast(bf16x8, *(const short8*)&Bsl[(nt * 16 + ln) * 40 + kq * 8]);
      acc[nt] = __builtin_amdgcn_mfma_f32_16x16x32_bf16(ah, bh, acc[nt], 0, 0, 0);
      acc[nt] = __builtin_amdgcn_mfma_f32_16x16x32_bf16(al, bh, acc[nt], 0, 0, 0);
      acc[nt] = __builtin_amdgcn_mfma_f32_16x16x32_bf16(ah, bl, acc[nt], 0, 0, 0);
    }
  }
#pragma unroll
  for (int nt = 0; nt < 4; ++nt) {
    const int npg = ntile * 64 + nt * 16 + ln;
    const float bs = biasp[npg];
#pragma unroll
    for (int r = 0; r < 4; ++r) {
      const int m = mtile * 64 + w * 16 + kq * 4 + r;
      const int s = m & 2047, b = m >> 11;
      xp[(size_t)(s * 32 + b) * 2048 + npg] = (__bf16)(acc[nt][r] + bs);
    }
  }
}

// ---------------------------------------------------------------------------
__global__ __launch_bounds__(256) void lstm_rec(
    const float* __restrict__ Whh, const int* __restrict__ lengths,
    const __bf16* __restrict__ xp, float* __restrict__ out,
    float* __restrict__ hid, unsigned* __restrict__ hpk,
    unsigned* __restrict__ cnt) {
  __shared__ short Hh[16 * 512];       // [m][k] bf16 hi, xor-swizzled granules
  __shared__ short Hl[16 * 512];
  __shared__ float Part[4 * 2 * 256];  // [wave][nt][m][n]
  __shared__ short Xps[2 * 512];       // xp double buffer [buf][m][n'' 0..31]

  const int tid = threadIdx.x;
  const int w = tid >> 6, lane = tid & 63, ln = lane & 15, kq = lane >> 4;
  const int bh = blockIdx.x >> 6;      // batch half (0..1)
  const int ug8 = blockIdx.x & 63;     // 8-unit group (0..63)
  const int b0 = bh * 16;
  unsigned* mycnt = cnt + bh * 128;    // 512B apart

  // Persistent W_hh fragments: tile nt covers gate-rows
  // rowg = (ln>>2)*512 + ug8*8 + nt*4 + (ln&3); K-slice of wave w.
  bf16x8 whi[2][4], wlo[2][4];
#pragma unroll
  for (int nt = 0; nt < 2; ++nt) {
    const int rowg = (ln >> 2) * 512 + ug8 * 8 + nt * 4 + (ln & 3);
#pragma unroll
    for (int kc = 0; kc < 4; ++kc) {
      const int k = w * 128 + kc * 32 + kq * 8;
      floatx4 f0 = *(const floatx4*)(Whh + (size_t)rowg * 512 + k);
      floatx4 f1 = *(const floatx4*)(Whh + (size_t)rowg * 512 + k + 4);
      float v[8] = {f0[0],f0[1],f0[2],f0[3],f1[0],f1[1],f1[2],f1[3]};
      cvt_hilo8(v, whi[nt][kc], wlo[nt][kc]);
    }
  }

  const int m_d = (tid & 63) >> 2, ul = tid & 3;  // wave0 elementwise ids
  int lenb = 0;
  if (tid < 64) lenb = lengths[b0 + m_d];
  float cst[2] = {0.f, 0.f};

  const int sm = tid >> 4, sq = tid & 15;  // h staging ids
  const int m2 = (tid - 64) >> 2, q2 = (tid - 64) & 3;  // wave1 xp ids

  // Initial xp[t=0] fill (wave1)
  if (w == 1) {
    short8 vv = *(const short8*)((const short*)xp +
        ((size_t)(b0 + m2)) * 2048 + ug8 * 32 + q2 * 8);
    *(short8*)&Xps[m2 * 32 + q2 * 8] = vv;
  }

  for (int t = 0; t < 2048; ++t) {
    // ---- stage h (packed dwords, LLC-coherent reads) -> LDS hi/lo planes ---
    {
      const unsigned* src = hpk + (t & 1) * 16384 + (size_t)(b0 + sm) * 512;
      unsigned long long v[16];
#pragma unroll
      for (int i = 0; i < 16; ++i) {
        const int g = sq + 16 * (i >> 2);
        v[i] = __hip_atomic_load(
            (const unsigned long long*)(src + g * 8 + (i & 3) * 2),
            __ATOMIC_RELAXED, __HIP_MEMORY_SCOPE_AGENT);
      }
#pragma unroll
      for (int gi = 0; gi < 4; ++gi) {
        const int g = sq + 16 * gi;
        short8 h8, l8;
#pragma unroll
        for (int j = 0; j < 4; ++j) {
          const unsigned w0 = (unsigned)v[gi * 4 + j];
          const unsigned w1 = (unsigned)(v[gi * 4 + j] >> 32);
          h8[j * 2]     = (short)(w0 >> 16);
          l8[j * 2]     = (short)(w0 & 0xffffu);
          h8[j * 2 + 1] = (short)(w1 >> 16);
          l8[j * 2 + 1] = (short)(w1 & 0xffffu);
        }
        const int d = sm * 512 + ((g ^ (sm & 7)) * 8);
        *(short8*)&Hh[d] = h8;
        *(short8*)&Hl[d] = l8;
      }
    }
    __syncthreads();
    // ---- MFMA: M=16 batches x N=16 gate-rows x 2 tiles, wave K-slice ----
    floatx4 acc[2] = {{0,0,0,0},{0,0,0,0}};
#pragma unroll
    for (int kc = 0; kc < 4; ++kc) {
      const int g = w * 16 + kc * 4 + kq;
      const int d = ln * 512 + ((g ^ (ln & 7)) * 8);
      bf16x8 ah = __builtin_bit_cast(bf16x8, *(const short8*)&Hh[d]);
      bf16x8 al = __builtin_bit_cast(bf16x8, *(const short8*)&Hl[d]);
#pragma unroll
      for (int nt = 0; nt < 2; ++nt) {
        acc[nt] = __builtin_amdgcn_mfma_f32_16x16x32_bf16(ah, whi[nt][kc], acc[nt], 0, 0, 0);
        acc[nt] = __builtin_amdgcn_mfma_f32_16x16x32_bf16(al, whi[nt][kc], acc[nt], 0, 0, 0);
        acc[nt] = __builtin_amdgcn_mfma_f32_16x16x32_bf16(ah, wlo[nt][kc], acc[nt], 0, 0, 0);
      }
    }
#pragma unroll
    for (int nt = 0; nt < 2; ++nt)
#pragma unroll
      for (int r = 0; r < 4; ++r)
        Part[w * 512 + nt * 256 + (kq * 4 + r) * 16 + ln] = acc[nt][r];
    // ---- wave1: prefetch xp for t+1 (off critical path) ----
    if (w == 1) {
      const int tp1 = (t + 1 < 2048) ? t + 1 : 2047;
      short8 vv = *(const short8*)((const short*)xp +
          ((size_t)(tp1 * 32 + b0 + m2)) * 2048 + ug8 * 32 + q2 * 8);
      *(short8*)&Xps[((t + 1) & 1) * 512 + m2 * 32 + q2 * 8] = vv;
    }
    __syncthreads();
    // ---- elementwise on wave0: (batch m_d, units nt*4+ul) ----
    if (tid < 64) {
      const int xb = (t & 1) * 512 + m_d * 32;
#pragma unroll
      for (int nt = 0; nt < 2; ++nt) {
        float pre[4];
#pragma unroll
        for (int g = 0; g < 4; ++g) {
          const int pi = nt * 256 + m_d * 16 + g * 4 + ul;
          const float xv = (float)__builtin_bit_cast(__bf16, Xps[xb + nt * 16 + g * 4 + ul]);
          pre[g] = xv + Part[pi] + Part[512 + pi] + Part[1024 + pi] + Part[1536 + pi];
        }
        const float gi_ = sigm(pre[0]);
        const float gf  = sigm(pre[1]);
        const float gg  = tanh_(pre[2]);
        const float go  = sigm(pre[3]);
        cst[nt] = gf * cst[nt] + gi_ * gg;
        const float hv = go * tanh_(cst[nt]);
        const int b = b0 + m_d, u = ug8 * 8 + nt * 4 + ul;
        out[((size_t)b * 2048 + t) * 512 + u] = (t < lenb) ? hv : 0.f;
        if (t == lenb - 1) hid[b * 512 + u] = hv;
        const __bf16 hb = (__bf16)hv;
        const __bf16 lb = (__bf16)(hv - (float)hb);
        const unsigned pk =
            ((unsigned)__builtin_bit_cast(unsigned short, hb) << 16) |
            (unsigned)__builtin_bit_cast(unsigned short, lb);
        __hip_atomic_store(hpk + ((t + 1) & 1) * 16384 + b * 512 + u, pk,
                           __ATOMIC_RELAXED, __HIP_MEMORY_SCOPE_AGENT);
      }
      asm volatile("s_waitcnt vmcnt(0)" ::: "memory");  // h stores done pre-arrive
    }
    // ---- per-half 64-WG barrier (no fences: data went through LLC) ----
    if (tid == 0) {
      __hip_atomic_fetch_add(mycnt, 1u, __ATOMIC_RELAXED, __HIP_MEMORY_SCOPE_AGENT);
      const unsigned tgt = 64u * (unsigned)(t + 1);
      while (__hip_atomic_load(mycnt, __ATOMIC_RELAXED, __HIP_MEMORY_SCOPE_AGENT) < tgt)
        __builtin_amdgcn_s_sleep(1);
    }
    __syncthreads();
  }
}

// ---------------------------------------------------------------------------
extern "C" void kernel_launch(void* const* d_in, const int* in_sizes, int n_in,
                              void* d_out, int out_size, void* d_ws, size_t ws_size,
                              hipStream_t stream) {
  const float* x = (const float*)d_in[0];
  const int* lengths = (const int*)d_in[1];
  const float* Wih = (const float*)d_in[2];
  const float* Whh = (const float*)d_in[3];
  const float* bih = (const float*)d_in[4];
  const float* bhh = (const float*)d_in[5];
  float* outf = (float*)d_out;
  char* ws = (char*)d_ws;
  if (ws_size < WS_NEED) return;

  float* biasp = (float*)(ws + BIAS_OFF);
  __bf16* xp = (__bf16*)(ws + XP_OFF);
  unsigned* hpk = (unsigned*)(ws + HPK_OFF);
  unsigned* cnt = (unsigned*)(ws + CNT_OFF);

  prep_kernel<<<1, 256, 0, stream>>>(bih, bhh, lengths, biasp, hpk, cnt, outf);
  xproj_gemm<<<32768, 256, 0, stream>>>(x, Wih, biasp, xp);
  lstm_rec<<<128, 256, 0, stream>>>(Whh, lengths, xp, outf,
                                    outf + HIDDEN_OFF_F, hpk, cnt);
}

// Round 4
// 7760.233 us; speedup vs baseline: 3.9560x; 1.4302x over previous
//
#include <hip/hip_runtime.h>

// ---------------------------------------------------------------------------
// LSTM B=32, S=2048, E=512, H=512 (gates 4H=2048), fp32 in/out.
//   prep_kernel : permuted bias, zero h planes + flags, lengths->floats.
//   xproj_gemm  : xp[t][b][n''] bf16 = x @ W_ih^T + bias (split-bf16 MFMA).
//                 n'' = (u>>2)*16 + (u&3)*4 + g  -> the 4 gate pre-acts of a
//                 (b,u) pair are CONTIGUOUS (one 8B load in the recurrence).
//   lstm_rec    : persistent, 64 WGs x 256 thr = two independent 32-WG clubs
//                 (one per batch half). WG = 16 units x 16 batches. W_hh in
//                 VGPRs (bf16 hi/lo split, 3-term MFMA). Per step:
//                   poll 32 flags (lane-parallel load, no RMW) ->
//                   coalesced 8B agent-atomic staging of packed h -> LDS ->
//                   MFMA (K split over 4 waves) -> LDS reduce ->
//                   elementwise on all 256 threads (1 (b,u) each) ->
//                   h publish (agent atomic) -> vmcnt drain -> flag store ->
//                   out[] store (off the critical path); hid kept in regs.
//                 ALL loads/stores compiler-tracked (R3's raw-asm loads with
//                 manual vmcnt raced: uses could be scheduled before the
//                 waitcnt). Only asm: the store-drain s_waitcnt (store-only).
// ---------------------------------------------------------------------------

typedef __attribute__((ext_vector_type(8))) __bf16 bf16x8;
typedef __attribute__((ext_vector_type(8))) short short8;
typedef __attribute__((ext_vector_type(4))) float floatx4;
typedef __attribute__((ext_vector_type(2))) unsigned uint32x2;

// ws layout (bytes)
#define XP_OFF   0ull
#define XP_BYTES (2048ull * 32ull * 2048ull * 2ull)   // 268,435,456
#define HPK_OFF  (XP_OFF + XP_BYTES)                  // 2 bufs x 32x512 dwords
#define HPK_BYTES (2ull * 16384ull * 4ull)
#define BIAS_OFF (HPK_OFF + HPK_BYTES)
#define FLAG_OFF (BIAS_OFF + 8192ull)                 // flags[2][32] dwords
#define WS_NEED  (FLAG_OFF + 256ull)

// d_out layout (fp32): out[32][2048][1][512], lengths[32], hidden[1][32][512]
#define LEN_OFF_F    33554432
#define HIDDEN_OFF_F 33554464

__device__ inline float sigm(float x) { return 1.f / (1.f + __expf(-x)); }
__device__ inline float tanh_(float x) {
  float e = __expf(-2.f * fabsf(x));
  float r = (1.f - e) / (1.f + e);
  return x >= 0.f ? r : -r;
}

__device__ inline void cvt_hilo8(const float* v, bf16x8& hi, bf16x8& lo) {
#pragma unroll
  for (int i = 0; i < 8; ++i) {
    __bf16 h = (__bf16)v[i];
    hi[i] = h;
    lo[i] = (__bf16)(v[i] - (float)h);
  }
}

__device__ inline float bf16f(unsigned short u) {
  union { unsigned u; float f; } c; c.u = ((unsigned)u) << 16; return c.f;
}

// ---------------------------------------------------------------------------
__global__ __launch_bounds__(256) void prep_kernel(
    const float* __restrict__ bih, const float* __restrict__ bhh,
    const int* __restrict__ len, float* __restrict__ biasp,
    unsigned* __restrict__ hpk, unsigned* __restrict__ flags,
    float* __restrict__ outf) {
  const int tid = threadIdx.x;
  for (int i = tid; i < 2048; i += 256) {
    // n'' = ug4*16 + ul*4 + g  ->  W row = g*512 + ug4*4 + ul
    int rowg = (i & 3) * 512 + (i >> 4) * 4 + ((i >> 2) & 3);
    biasp[i] = bih[rowg] + bhh[rowg];
  }
  for (int i = tid; i < 32768; i += 256) hpk[i] = 0u;
  if (tid < 64) flags[tid] = 0u;
  if (tid < 32) outf[LEN_OFF_F + tid] = (float)len[tid];
}

// ---------------------------------------------------------------------------
// xp GEMM: M=65536 (b*2048+s), N=2048 (n''), K=512. Tile 64x64, BK=32.
__global__ __launch_bounds__(256) void xproj_gemm(
    const float* __restrict__ x, const float* __restrict__ Wih,
    const float* __restrict__ biasp, __bf16* __restrict__ xp) {
  __shared__ short Ash[64 * 40], Asl[64 * 40], Bsh[64 * 40], Bsl[64 * 40];
  const int tid = threadIdx.x;
  const int w = tid >> 6, lane = tid & 63, ln = lane & 15, kq = lane >> 4;
  const int ntile = blockIdx.x & 31, mtile = blockIdx.x >> 5;
  const int srow = tid >> 2, sseg = tid & 3;

  const size_t a_base = (size_t)(mtile * 64 + srow) * 512 + sseg * 8;
  const int np_s = ntile * 64 + srow;
  const int rowg = (np_s & 3) * 512 + (np_s >> 4) * 4 + ((np_s >> 2) & 3);
  const size_t b_base = (size_t)rowg * 512 + sseg * 8;

  floatx4 acc[4] = {{0,0,0,0},{0,0,0,0},{0,0,0,0},{0,0,0,0}};

  for (int k0 = 0; k0 < 512; k0 += 32) {
    floatx4 a0 = *(const floatx4*)(x + a_base + k0);
    floatx4 a1 = *(const floatx4*)(x + a_base + k0 + 4);
    floatx4 b0 = *(const floatx4*)(Wih + b_base + k0);
    floatx4 b1 = *(const floatx4*)(Wih + b_base + k0 + 4);
    __syncthreads();
    {
      float va[8] = {a0[0],a0[1],a0[2],a0[3],a1[0],a1[1],a1[2],a1[3]};
      bf16x8 hi, lo; cvt_hilo8(va, hi, lo);
      *(short8*)&Ash[srow * 40 + sseg * 8] = __builtin_bit_cast(short8, hi);
      *(short8*)&Asl[srow * 40 + sseg * 8] = __builtin_bit_cast(short8, lo);
      float vb[8] = {b0[0],b0[1],b0[2],b0[3],b1[0],b1[1],b1[2],b1[3]};
      cvt_hilo8(vb, hi, lo);
      *(short8*)&Bsh[srow * 40 + sseg * 8] = __builtin_bit_cast(short8, hi);
      *(short8*)&Bsl[srow * 40 + sseg * 8] = __builtin_bit_cast(short8, lo);
    }
    __syncthreads();
    bf16x8 ah = __builtin_bit_cast(bf16x8, *(const short8*)&Ash[(16 * w + ln) * 40 + kq * 8]);
    bf16x8 al = __builtin_bit_cast(bf16x8, *(const short8*)&Asl[(16 * w + ln) * 40 + kq * 8]);
#pragma unroll
    for (int nt = 0; nt < 4; ++nt) {
      bf16x8 bh = __builtin_bit_cast(bf16x8, *(const short8*)&Bsh[(nt * 16 + ln) * 40 + kq * 8]);
      bf16x8 bl = __builtin_bit_cast(bf16x8, *(const short8*)&Bsl[(nt * 16 + ln) * 40 + kq * 8]);
      acc[nt] = __builtin_amdgcn_mfma_f32_16x16x32_bf16(ah, bh, acc[nt], 0, 0, 0);
      acc[nt] = __builtin_amdgcn_mfma_f32_16x16x32_bf16(al, bh, acc[nt], 0, 0, 0);
      acc[nt] = __builtin_amdgcn_mfma_f32_16x16x32_bf16(ah, bl, acc[nt], 0, 0, 0);
    }
  }
#pragma unroll
  for (int nt = 0; nt < 4; ++nt) {
    const int npg = ntile * 64 + nt * 16 + ln;
    const float bs = biasp[npg];
#pragma unroll
    for (int r = 0; r < 4; ++r) {
      const int m = mtile * 64 + w * 16 + kq * 4 + r;
      const int s = m & 2047, b = m >> 11;
      xp[(size_t)(s * 32 + b) * 2048 + npg] = (__bf16)(acc[nt][r] + bs);
    }
  }
}

// ---------------------------------------------------------------------------
__global__ __launch_bounds__(256, 1) void lstm_rec(
    const float* __restrict__ Whh, const int* __restrict__ lengths,
    const __bf16* __restrict__ xp, float* __restrict__ out,
    float* __restrict__ hid, unsigned* __restrict__ hpk,
    unsigned* __restrict__ flags) {
  __shared__ short Hh[16 * 512];       // [m][k] bf16 hi, xor-swizzled granules
  __shared__ short Hl[16 * 512];
  __shared__ float Part[4 * 1088];     // [wave][nt(272 pad)][m][n]

  const int tid = threadIdx.x;
  const int w = tid >> 6, lane = tid & 63, ln = lane & 15, kq = lane >> 4;
  const int bh = blockIdx.x >> 5;      // batch half
  const int ug = blockIdx.x & 31;      // 16-unit group
  const int b0 = bh * 16;

  // Persistent W_hh frags. Tile nt, lane ln: g=ln&3, ul=ln>>2,
  // unit = ug*16 + nt*4 + ul, row = g*512 + unit. K-slice of wave w.
  bf16x8 whi[4][4], wlo[4][4];
#pragma unroll
  for (int nt = 0; nt < 4; ++nt) {
    const int rowg = (ln & 3) * 512 + (ug * 4 + nt) * 4 + (ln >> 2);
#pragma unroll
    for (int kc = 0; kc < 4; ++kc) {
      const int k = w * 128 + kc * 32 + kq * 8;
      floatx4 f0 = *(const floatx4*)(Whh + (size_t)rowg * 512 + k);
      floatx4 f1 = *(const floatx4*)(Whh + (size_t)rowg * 512 + k + 4);
      float v[8] = {f0[0],f0[1],f0[2],f0[3],f1[0],f1[1],f1[2],f1[3]};
      cvt_hilo8(v, whi[nt][kc], wlo[nt][kc]);
    }
  }

  // Elementwise ownership: 1 (batch,unit) per thread.
  const int m_e = tid >> 4, ue = tid & 15;
  const int b_e = b0 + m_e, u_e = ug * 16 + ue;
  const int lenb = lengths[b_e];
  float cst = 0.f, hcap = 0.f;

  // xp: this thread's 4 gate pre-acts are 8B contiguous (plain cached loads).
  const __bf16* xpb = xp + (size_t)b_e * 2048 + ug * 64 + (ue >> 2) * 16 + (ue & 3) * 4;
  uint32x2 xpcur = *(const uint32x2*)xpb;  // t = 0
  uint32x2 xpnext;

  unsigned* myflag = flags + bh * 32 + ug;
  const unsigned* pollp = flags + bh * 32 + (lane & 31);

  for (int t = 0; t < 2048; ++t) {
    // ---- poll: all 32 producer flags >= t (lane-parallel, no RMW) ----
    if (w == 0 && t > 0) {
      for (;;) {
        unsigned f = __hip_atomic_load(pollp, __ATOMIC_RELAXED,
                                       __HIP_MEMORY_SCOPE_AGENT);
        if (__ballot(f < (unsigned)t) == 0ull) break;
        __builtin_amdgcn_s_sleep(1);
      }
    }
    __syncthreads();
    // ---- stage packed h: 16 x 8B agent atomics, coalesced 1KB/wave-row ----
    const unsigned* src = hpk + (t & 1) * 16384 + b0 * 512;
    unsigned long long v[16];
#pragma unroll
    for (int k = 0; k < 16; ++k)
      v[k] = __hip_atomic_load(
          (const unsigned long long*)(src + k * 512 + tid * 2),
          __ATOMIC_RELAXED, __HIP_MEMORY_SCOPE_AGENT);
    // xp prefetch for t+1 (compiler-tracked; consumed next iteration)
    {
      const int tn = (t + 1 < 2048) ? t + 1 : 2047;
      xpnext = *(const uint32x2*)(xpb + (size_t)tn * 65536);
    }
    // ---- unpack hi/lo -> swizzled LDS planes (2-way-free bank pattern) ----
    {
      const int g = tid >> 2;  // 8-unit granule of units (tid*2, tid*2+1)
#pragma unroll
      for (int k = 0; k < 16; ++k) {
        const unsigned w0 = (unsigned)v[k], w1 = (unsigned)(v[k] >> 32);
        const int d = k * 512 + ((g ^ (k & 7)) * 8) + (tid & 3) * 2;
        *(unsigned*)&Hh[d] = (w0 >> 16) | (w1 & 0xffff0000u);
        *(unsigned*)&Hl[d] = (w0 & 0xffffu) | (w1 << 16);
      }
    }
    __syncthreads();
    // ---- MFMA: M=16 batches x N=16 gate-rows x 4 tiles, wave K-slice ----
    floatx4 acc[4] = {{0,0,0,0},{0,0,0,0},{0,0,0,0},{0,0,0,0}};
#pragma unroll
    for (int kc = 0; kc < 4; ++kc) {
      const int g = w * 16 + kc * 4 + kq;
      const int d = ln * 512 + ((g ^ (ln & 7)) * 8);
      bf16x8 ah = __builtin_bit_cast(bf16x8, *(const short8*)&Hh[d]);
      bf16x8 al = __builtin_bit_cast(bf16x8, *(const short8*)&Hl[d]);
#pragma unroll
      for (int nt = 0; nt < 4; ++nt) {
        acc[nt] = __builtin_amdgcn_mfma_f32_16x16x32_bf16(ah, whi[nt][kc], acc[nt], 0, 0, 0);
        acc[nt] = __builtin_amdgcn_mfma_f32_16x16x32_bf16(al, whi[nt][kc], acc[nt], 0, 0, 0);
        acc[nt] = __builtin_amdgcn_mfma_f32_16x16x32_bf16(ah, wlo[nt][kc], acc[nt], 0, 0, 0);
      }
    }
#pragma unroll
    for (int nt = 0; nt < 4; ++nt)
#pragma unroll
      for (int r4 = 0; r4 < 4; ++r4)
        Part[w * 1088 + nt * 272 + (kq * 4 + r4) * 16 + ln] = acc[nt][r4];
    __syncthreads();
    // ---- reduce + gates + state (all 256 threads, one (b,u) each) ----
    {
      const int pb = (ue >> 2) * 272 + m_e * 16 + (ue & 3) * 4;
      floatx4 p0 = *(const floatx4*)&Part[pb];
      floatx4 p1 = *(const floatx4*)&Part[1088 + pb];
      floatx4 p2 = *(const floatx4*)&Part[2176 + pb];
      floatx4 p3 = *(const floatx4*)&Part[3264 + pb];
      const float xg0 = bf16f((unsigned short)(xpcur[0] & 0xffffu));
      const float xg1 = bf16f((unsigned short)(xpcur[0] >> 16));
      const float xg2 = bf16f((unsigned short)(xpcur[1] & 0xffffu));
      const float xg3 = bf16f((unsigned short)(xpcur[1] >> 16));
      const float pi = xg0 + p0[0] + p1[0] + p2[0] + p3[0];
      const float pf = xg1 + p0[1] + p1[1] + p2[1] + p3[1];
      const float pg = xg2 + p0[2] + p1[2] + p2[2] + p3[2];
      const float po = xg3 + p0[3] + p1[3] + p2[3] + p3[3];
      const float gi_ = sigm(pi), gf = sigm(pf), gg = tanh_(pg), go = sigm(po);
      cst = gf * cst + gi_ * gg;
      const float hv = go * tanh_(cst);
      // publish h (packed hi/lo) to the other buffer
      const __bf16 hb = (__bf16)hv;
      const __bf16 lb = (__bf16)(hv - (float)hb);
      const unsigned pk =
          ((unsigned)__builtin_bit_cast(unsigned short, hb) << 16) |
          (unsigned)__builtin_bit_cast(unsigned short, lb);
      __hip_atomic_store(hpk + ((t + 1) & 1) * 16384 + b_e * 512 + u_e, pk,
                         __ATOMIC_RELAXED, __HIP_MEMORY_SCOPE_AGENT);
      asm volatile("s_waitcnt vmcnt(0)" ::: "memory");  // h store drained
      __syncthreads();                                  // ...by ALL waves
      if (tid == 0)
        __hip_atomic_store(myflag, (unsigned)(t + 1), __ATOMIC_RELAXED,
                           __HIP_MEMORY_SCOPE_AGENT);
      // off-path stores: out now, hid captured in a register
      out[((size_t)b_e * 2048 + t) * 512 + u_e] = (t < lenb) ? hv : 0.f;
      if (t == lenb - 1) hcap = hv;
    }
    xpcur = xpnext;
  }
  hid[b_e * 512 + u_e] = hcap;
}

// ---------------------------------------------------------------------------
extern "C" void kernel_launch(void* const* d_in, const int* in_sizes, int n_in,
                              void* d_out, int out_size, void* d_ws, size_t ws_size,
                              hipStream_t stream) {
  const float* x = (const float*)d_in[0];
  const int* lengths = (const int*)d_in[1];
  const float* Wih = (const float*)d_in[2];
  const float* Whh = (const float*)d_in[3];
  const float* bih = (const float*)d_in[4];
  const float* bhh = (const float*)d_in[5];
  float* outf = (float*)d_out;
  char* ws = (char*)d_ws;
  if (ws_size < WS_NEED) return;

  float* biasp = (float*)(ws + BIAS_OFF);
  __bf16* xp = (__bf16*)(ws + XP_OFF);
  unsigned* hpk = (unsigned*)(ws + HPK_OFF);
  unsigned* flags = (unsigned*)(ws + FLAG_OFF);

  prep_kernel<<<1, 256, 0, stream>>>(bih, bhh, lengths, biasp, hpk, flags, outf);
  xproj_gemm<<<32768, 256, 0, stream>>>(x, Wih, biasp, xp);
  lstm_rec<<<64, 256, 0, stream>>>(Whh, lengths, xp, outf,
                                   outf + HIDDEN_OFF_F, hpk, flags);
}